// Round 6
// baseline (687.729 us; speedup 1.0000x reference)
//
#include <hip/hip_runtime.h>
#include <hip/hip_bf16.h>
#include <cstdint>
#include <cstddef>

// ParallelFLAAttention: B=2,N=2048,HID=2048,H=16,KVH=4,D=128,GROUPS=4
// out = softmax_causal(QK^T*s)V @ Wo + 0.01 * GLA(q,k,v)
// I/O f32; internal bf16 MFMA + f32 accum.
// Base attention: fixed-max softmax, wave-autonomous (no barriers/LDS staging).
// FLA: factorized chunk form (T=32): o = q~ S0 + tril(q~ k~^T) v, all MFMA.

typedef __attribute__((ext_vector_type(4))) float f32x4;
typedef __attribute__((ext_vector_type(8))) short s16x8;
typedef unsigned short u16;

__device__ __forceinline__ float bfu2f(u16 u) {
  union { unsigned int i; float f; } x; x.i = ((unsigned int)u) << 16; return x.f;
}
__device__ __forceinline__ u16 f2bfu(float f) {
  union { float f; unsigned int i; } x; x.f = f;
  unsigned int r = x.i + 0x7fffu + ((x.i >> 16) & 1u);
  return (u16)(r >> 16);
}
__device__ __forceinline__ void bf8_to_f(s16x8 v, float* o) {
  union { s16x8 v; u16 u[8]; } x; x.v = v;
#pragma unroll
  for (int j = 0; j < 8; j++) o[j] = bfu2f(x.u[j]);
}
__device__ __forceinline__ s16x8 pack_bf8(f32x4 lo, f32x4 hi) {
  union { s16x8 v; u16 u[8]; } x;
#pragma unroll
  for (int j = 0; j < 4; j++) { x.u[j] = f2bfu(lo[j]); x.u[4 + j] = f2bfu(hi[j]); }
  return x.v;
}
__device__ __forceinline__ void gload_lds16(const u16* g, u16* l) {
  __builtin_amdgcn_global_load_lds(
      (__attribute__((address_space(1))) void*)(g),
      (__attribute__((address_space(3))) void*)(l), 16, 0, 0);
}

// ---------------------------------------------------------------- utility
__global__ __launch_bounds__(256) void f32_to_bf16(
    const float* __restrict__ src, u16* __restrict__ dst, int n8) {
  const int i = blockIdx.x * 256 + threadIdx.x;
  if (i < n8) {
    f32x4 a = *(const f32x4*)(src + (size_t)i * 8);
    f32x4 b = *(const f32x4*)(src + (size_t)i * 8 + 4);
    *(s16x8*)(dst + (size_t)i * 8) = pack_bf8(a, b);
  }
}

// ---------------------------------------------------------------- transposes
__global__ __launch_bounds__(256) void transpose_f32_bf16(
    const float* __restrict__ src, u16* __restrict__ dst, int R, int C) {
  __shared__ u16 tile[32][33];
  const int bx = blockIdx.x * 32, by = blockIdx.y * 32;
  const int tx = threadIdx.x & 31, ty = threadIdx.x >> 5;  // 32 x 8
#pragma unroll
  for (int i = 0; i < 32; i += 8)
    tile[ty + i][tx] = f2bfu(src[(size_t)(by + ty + i) * C + bx + tx]);
  __syncthreads();
#pragma unroll
  for (int i = 0; i < 32; i += 8)
    dst[(size_t)(bx + ty + i) * R + by + tx] = tile[tx][ty + i];
}

__global__ __launch_bounds__(256) void transpose_bf16(
    const u16* __restrict__ src, u16* __restrict__ dst, int R, int C) {
  __shared__ u16 tile[32][33];
  const int bx = blockIdx.x * 32, by = blockIdx.y * 32;
  const int tx = threadIdx.x & 31, ty = threadIdx.x >> 5;
#pragma unroll
  for (int i = 0; i < 32; i += 8)
    tile[ty + i][tx] = src[(size_t)(by + ty + i) * C + bx + tx];
  __syncthreads();
#pragma unroll
  for (int i = 0; i < 32; i += 8)
    dst[(size_t)(bx + ty + i) * R + by + tx] = tile[tx][ty + i];
}

// ---------------------------------------------------------------- GEMM (m97 structure)
__global__ __launch_bounds__(256) void gemm_t(
    const u16* __restrict__ A, const u16* __restrict__ Bt0, const u16* __restrict__ Bt1,
    u16* __restrict__ Cb0, u16* __restrict__ Cb1, float* __restrict__ Cf,
    int M, int N, int K, const u16* __restrict__ addsrc, float addw) {
  __shared__ u16 Al[128 * 32];
  __shared__ u16 Bl[128 * 32];
  const u16* Bt = blockIdx.z ? Bt1 : Bt0;
  u16* Cb = blockIdx.z ? Cb1 : Cb0;
  const int m0 = blockIdx.y * 128, n0 = blockIdx.x * 128;
  const int t = threadIdx.x, w = t >> 6, l = t & 63, lm = l & 15, lq = l >> 4;
  const int wr = w >> 1, wc = w & 1;
  const f32x4 z4 = {0.f, 0.f, 0.f, 0.f};
  f32x4 acc[4][4];
#pragma unroll
  for (int i = 0; i < 4; i++)
#pragma unroll
    for (int j = 0; j < 4; j++) acc[i][j] = z4;
  const int srow = l >> 2, scol = (l & 3) * 8;
  const u16* Ag = A + (size_t)(m0 + w * 32 + srow) * K + scol;
  const u16* Bg = Bt + (size_t)(n0 + w * 32 + srow) * K + scol;
  u16* Alw = &Al[(w * 32) * 32];
  u16* Blw = &Bl[(w * 32) * 32];
  for (int kk = 0; kk < K; kk += 32) {
    gload_lds16(Ag + kk, Alw);
    gload_lds16(Ag + (size_t)16 * K + kk, Alw + 16 * 32);
    gload_lds16(Bg + kk, Blw);
    gload_lds16(Bg + (size_t)16 * K + kk, Blw + 16 * 32);
    __syncthreads();
    s16x8 af[4], bfr[4];
#pragma unroll
    for (int sm = 0; sm < 4; sm++) af[sm] = *(const s16x8*)&Al[(wr * 64 + sm * 16 + lm) * 32 + lq * 8];
#pragma unroll
    for (int sn = 0; sn < 4; sn++) bfr[sn] = *(const s16x8*)&Bl[(wc * 64 + sn * 16 + lm) * 32 + lq * 8];
#pragma unroll
    for (int sm = 0; sm < 4; sm++)
#pragma unroll
      for (int sn = 0; sn < 4; sn++)
        acc[sm][sn] = __builtin_amdgcn_mfma_f32_16x16x32_bf16(af[sm], bfr[sn], acc[sm][sn], 0, 0, 0);
    __syncthreads();
  }
#pragma unroll
  for (int sm = 0; sm < 4; sm++)
#pragma unroll
    for (int sn = 0; sn < 4; sn++)
#pragma unroll
      for (int r = 0; r < 4; r++) {
        const int row = m0 + wr * 64 + sm * 16 + lq * 4 + r;
        const int col = n0 + wc * 64 + sn * 16 + lm;
        float v = acc[sm][sn][r];
        if (Cf) {
          if (addsrc) v += addw * bfu2f(addsrc[(size_t)row * N + col]);
          Cf[(size_t)row * N + col] = v;
        } else {
          Cb[(size_t)row * N + col] = f2bfu(v);
        }
      }
}

// ---------------------------------------------------------------- flash attention, wave-autonomous
__global__ __launch_bounds__(256) void flash_attn_wave(
    const u16* __restrict__ Q, const u16* __restrict__ Kx,
    const u16* __restrict__ Vt, u16* __restrict__ AO) {
  __shared__ u16 Pl[4][2][16][68];
  const int bid = blockIdx.x;
  const int set = bid & 7;               // b*4 + kvh
  const int b = set >> 2, kvh = set & 3;
  const int t = threadIdx.x, w = t >> 6, l = t & 63, lm = l & 15, lq = l >> 4;
  const int wid = (bid >> 3) * 4 + w;    // 0..127 within set
  const int h = kvh * 4 + (wid & 3);
  const int pair = wid >> 2;             // 0..31
  const float scale = 0.0883883476483184f;  // 1/sqrt(128)
  const u16* Kbase = Kx + (size_t)(b * 2048) * 512 + kvh * 128;
  const u16* Vbase = Vt + (size_t)(b * 512 + kvh * 128) * 2048;
  const f32x4 z4 = {0.f, 0.f, 0.f, 0.f};
#pragma unroll 1
  for (int half = 0; half < 2; half++) {
    const int c = half ? (63 - pair) : pair;
    const int base = c * 32;
    const int kthi = c >> 1;
    s16x8 qf[2][4];
#pragma unroll
    for (int m = 0; m < 2; m++)
#pragma unroll
      for (int kk = 0; kk < 4; kk++)
        qf[m][kk] = *(const s16x8*)(Q + ((size_t)(b * 2048 + base + m * 16 + lm)) * 2048 +
                                    h * 128 + kk * 32 + lq * 8);
    f32x4 oacc[2][8];
#pragma unroll
    for (int m = 0; m < 2; m++)
#pragma unroll
      for (int e = 0; e < 8; e++) oacc[m][e] = z4;
    float lsum[2][4] = {{0.f, 0.f, 0.f, 0.f}, {0.f, 0.f, 0.f, 0.f}};
#pragma unroll 1
    for (int kt = 0; kt <= kthi; kt++) {
      const int n0 = kt * 64;
      s16x8 kf[4][4];
#pragma unroll
      for (int nst = 0; nst < 4; nst++)
#pragma unroll
        for (int kk = 0; kk < 4; kk++)
          kf[nst][kk] = *(const s16x8*)(Kbase + (size_t)(n0 + nst * 16 + lm) * 512 +
                                        kk * 32 + lq * 8);
      f32x4 sacc[2][4];
#pragma unroll
      for (int m = 0; m < 2; m++)
#pragma unroll
        for (int i = 0; i < 4; i++) sacc[m][i] = z4;
#pragma unroll
      for (int m = 0; m < 2; m++)
#pragma unroll
        for (int nst = 0; nst < 4; nst++)
#pragma unroll
          for (int kk = 0; kk < 4; kk++)
            sacc[m][nst] = __builtin_amdgcn_mfma_f32_16x16x32_bf16(
                qf[m][kk], kf[nst][kk], sacc[m][nst], 0, 0, 0);
      const bool diag = (kt == kthi);
#pragma unroll
      for (int m = 0; m < 2; m++)
#pragma unroll
        for (int r = 0; r < 4; r++) {
          const int qrow = base + m * 16 + lq * 4 + r;
#pragma unroll
          for (int nst = 0; nst < 4; nst++) {
            float p = __expf(sacc[m][nst][r] * scale);
            if (diag && (n0 + nst * 16 + lm > qrow)) p = 0.f;
            lsum[m][r] += p;
            Pl[w][m][lq * 4 + r][nst * 16 + lm] = f2bfu(p);
          }
        }
      s16x8 vf[8][2];
#pragma unroll
      for (int et = 0; et < 8; et++)
#pragma unroll
        for (int kc = 0; kc < 2; kc++)
          vf[et][kc] = *(const s16x8*)(Vbase + (size_t)(et * 16 + lm) * 2048 +
                                       n0 + kc * 32 + lq * 8);
      s16x8 pf[2][2];
#pragma unroll
      for (int m = 0; m < 2; m++)
#pragma unroll
        for (int kc = 0; kc < 2; kc++)
          pf[m][kc] = *(const s16x8*)&Pl[w][m][lm][kc * 32 + lq * 8];
#pragma unroll
      for (int m = 0; m < 2; m++)
#pragma unroll
        for (int et = 0; et < 8; et++)
#pragma unroll
          for (int kc = 0; kc < 2; kc++)
            oacc[m][et] = __builtin_amdgcn_mfma_f32_16x16x32_bf16(
                pf[m][kc], vf[et][kc], oacc[m][et], 0, 0, 0);
    }
#pragma unroll
    for (int m = 0; m < 2; m++)
#pragma unroll
      for (int r = 0; r < 4; r++) {
#pragma unroll
        for (int off = 1; off < 16; off <<= 1)
          lsum[m][r] += __shfl_xor(lsum[m][r], off, 64);
      }
#pragma unroll
    for (int m = 0; m < 2; m++)
#pragma unroll
      for (int r = 0; r < 4; r++) {
        const float inv = 1.f / lsum[m][r];
        const int row = base + m * 16 + lq * 4 + r;
        u16* op = AO + ((size_t)(b * 2048 + row)) * 2048 + h * 128;
#pragma unroll
        for (int et = 0; et < 8; et++) op[et * 16 + lm] = f2bfu(oacc[m][et][r] * inv);
      }
  }
}

// ---------------------------------------------------------------- FLA: per-32-chunk gates + contribution
// grid (c=64, kvh=4, b=2). Computes G (cumprod sigmoid gates), k~=k/G, Lam=G_end,
// and M^T[e][d] = sum_s v[s,e] khat[s,d] via MFMA (khat = k~ * Lam).
__global__ __launch_bounds__(256) void fla_contrib32(
    const u16* __restrict__ Kx, const u16* __restrict__ Vt,
    u16* __restrict__ Gg, u16* __restrict__ Ktg, u16* __restrict__ MT,
    float* __restrict__ Lam) {
  __shared__ float gl[32][132];
  __shared__ float kl[32][132];
  __shared__ float ktl[32][132];
  __shared__ u16 khT[128][40];
  const int c = blockIdx.x, kvh = blockIdx.y, b = blockIdx.z;
  const int bk = b * 4 + kvh;
  const int t = threadIdx.x;
  const size_t cb = (size_t)bk * 64 + c;
  {
    const int r = t >> 3, c0 = (t & 7) * 16;
    const u16* kp = Kx + ((size_t)(b * 2048 + c * 32 + r)) * 512 + kvh * 128 + c0;
#pragma unroll
    for (int i = 0; i < 2; i++) {
      float kv[8];
      bf8_to_f(*(const s16x8*)(kp + i * 8), kv);
#pragma unroll
      for (int j = 0; j < 8; j++) {
        kl[r][c0 + i * 8 + j] = kv[j];
        gl[r][c0 + i * 8 + j] = 1.f / (1.f + __expf(-kv[j]));
      }
    }
  }
  __syncthreads();
  if (t < 128) {  // one thread per d: cumprod + ktilde + khat^T
    float G = 1.f;
#pragma unroll
    for (int s = 0; s < 32; s++) {
      G *= gl[s][t];
      gl[s][t] = G;               // in-place: gl now holds G_t
      ktl[s][t] = kl[s][t] / G;
    }
    Lam[cb * 128 + t] = G;
    const float lam = G;
#pragma unroll
    for (int s = 0; s < 32; s++) khT[t][s] = f2bfu(ktl[s][t] * lam);
  }
  __syncthreads();
  // vectorized G / ktilde stores (bf16)
  {
    const int r = t >> 3, c0 = (t & 7) * 16;
    u16* gp = Gg + cb * 4096 + r * 128 + c0;
    u16* kp = Ktg + cb * 4096 + r * 128 + c0;
#pragma unroll
    for (int i = 0; i < 2; i++) {
      f32x4 a = *(f32x4*)&gl[r][c0 + i * 8];
      f32x4 b2 = *(f32x4*)&gl[r][c0 + i * 8 + 4];
      *(s16x8*)(gp + i * 8) = pack_bf8(a, b2);
      a = *(f32x4*)&ktl[r][c0 + i * 8];
      b2 = *(f32x4*)&ktl[r][c0 + i * 8 + 4];
      *(s16x8*)(kp + i * 8) = pack_bf8(a, b2);
    }
  }
  // M^T = v^T @ khat via MFMA; wave w owns e-tiles {2w,2w+1}, all 8 d-tiles
  const int w = t >> 6, l = t & 63, lm = l & 15, lq = l >> 4;
  const f32x4 z4 = {0.f, 0.f, 0.f, 0.f};
  f32x4 macc[2][8];
#pragma unroll
  for (int ei = 0; ei < 2; ei++)
#pragma unroll
    for (int dt = 0; dt < 8; dt++) macc[ei][dt] = z4;
  s16x8 vtf[2];
#pragma unroll
  for (int ei = 0; ei < 2; ei++) {
    const int et = w * 2 + ei;
    vtf[ei] = *(const s16x8*)(Vt + ((size_t)(b * 512 + kvh * 128 + et * 16 + lm)) * 2048 +
                              c * 32 + lq * 8);
  }
#pragma unroll
  for (int dt = 0; dt < 8; dt++) {
    s16x8 kf = *(const s16x8*)&khT[dt * 16 + lm][lq * 8];
#pragma unroll
    for (int ei = 0; ei < 2; ei++)
      macc[ei][dt] = __builtin_amdgcn_mfma_f32_16x16x32_bf16(vtf[ei], kf, macc[ei][dt], 0, 0, 0);
  }
  u16* mp = MT + cb * 16384;
#pragma unroll
  for (int ei = 0; ei < 2; ei++)
#pragma unroll
    for (int dt = 0; dt < 8; dt++)
#pragma unroll
      for (int r = 0; r < 4; r++)
        mp[(size_t)((w * 2 + ei) * 16 + lq * 4 + r) * 128 + dt * 16 + lm] =
            f2bfu(macc[ei][dt][r]);
}

// ---------------------------------------------------------------- FLA prefix: S^T checkpoints per 32-chunk
__global__ __launch_bounds__(256) void fla_prefix32(
    const u16* __restrict__ MT, const float* __restrict__ Lam, u16* __restrict__ SwsT) {
  const int bk = blockIdx.x;
  const int t = threadIdx.x;
  const int e = t >> 1, d0 = (t & 1) * 64;
  float S[64];
#pragma unroll
  for (int i = 0; i < 64; i++) S[i] = 0.f;
  for (int c = 0; c < 64; c++) {
    const size_t cb = (size_t)bk * 64 + c;
    u16* sp = SwsT + cb * 16384 + e * 128 + d0;
#pragma unroll
    for (int i = 0; i < 8; i++) {
      f32x4 a = {S[i * 8], S[i * 8 + 1], S[i * 8 + 2], S[i * 8 + 3]};
      f32x4 b2 = {S[i * 8 + 4], S[i * 8 + 5], S[i * 8 + 6], S[i * 8 + 7]};
      *(s16x8*)(sp + i * 8) = pack_bf8(a, b2);
    }
    const float* lp = Lam + cb * 128 + d0;
    const u16* mp = MT + cb * 16384 + e * 128 + d0;
#pragma unroll
    for (int i = 0; i < 64; i += 8) {
      float mv[8];
      bf8_to_f(*(const s16x8*)(mp + i), mv);
#pragma unroll
      for (int j = 0; j < 8; j++) S[i + j] = S[i + j] * lp[i + j] + mv[j];
    }
  }
}

// ---------------------------------------------------------------- FLA output: O = scale*(q~ S0 + tril(q~ k~^T) v)
// grid (c=64, h=16, b=2); all fragments direct from global; per-wave A round trip in LDS.
__global__ __launch_bounds__(256) void fla_output_mfma(
    const u16* __restrict__ Q, const u16* __restrict__ Gg, const u16* __restrict__ Ktg,
    const u16* __restrict__ SwsT, const u16* __restrict__ Vt, u16* __restrict__ Fla) {
  __shared__ u16 Pl[4][2][16][40];
  const int c = blockIdx.x, h = blockIdx.y, b = blockIdx.z;
  const int kvh = h >> 2, bk = b * 4 + kvh;
  const int t = threadIdx.x, w = t >> 6, l = t & 63, lm = l & 15, lq = l >> 4;
  const float scale = 0.0883883476483184f;
  const size_t cb = (size_t)bk * 64 + c;
  const f32x4 z4 = {0.f, 0.f, 0.f, 0.f};
  // q~ A-frags: q * G (both bf16 global), repacked bf16
  s16x8 qgf[2][4];
#pragma unroll
  for (int m = 0; m < 2; m++)
#pragma unroll
    for (int kk = 0; kk < 4; kk++) {
      float qv[8], gv[8];
      bf8_to_f(*(const s16x8*)(Q + ((size_t)(b * 2048 + c * 32 + m * 16 + lm)) * 2048 +
                               h * 128 + kk * 32 + lq * 8), qv);
      bf8_to_f(*(const s16x8*)(Gg + cb * 4096 + (m * 16 + lm) * 128 + kk * 32 + lq * 8), gv);
      f32x4 a, b2;
#pragma unroll
      for (int j = 0; j < 4; j++) { a[j] = qv[j] * gv[j]; b2[j] = qv[4 + j] * gv[4 + j]; }
      qgf[m][kk] = pack_bf8(a, b2);
    }
  // A = q~ @ k~^T  (k~ B-frags direct from global)
  f32x4 sacc[2][2];
#pragma unroll
  for (int m = 0; m < 2; m++)
#pragma unroll
    for (int st = 0; st < 2; st++) sacc[m][st] = z4;
#pragma unroll
  for (int st = 0; st < 2; st++)
#pragma unroll
    for (int kk = 0; kk < 4; kk++) {
      s16x8 ktf = *(const s16x8*)(Ktg + cb * 4096 + (st * 16 + lm) * 128 + kk * 32 + lq * 8);
#pragma unroll
      for (int m = 0; m < 2; m++)
        sacc[m][st] = __builtin_amdgcn_mfma_f32_16x16x32_bf16(qgf[m][kk], ktf, sacc[m][st], 0, 0, 0);
    }
  // causal mask (s<=t within chunk) + C->A layout round trip
#pragma unroll
  for (int m = 0; m < 2; m++)
#pragma unroll
    for (int st = 0; st < 2; st++)
#pragma unroll
      for (int r = 0; r < 4; r++) {
        const int trow = m * 16 + lq * 4 + r;
        const int scol = st * 16 + lm;
        Pl[w][m][lq * 4 + r][st * 16 + lm] = f2bfu(scol <= trow ? sacc[m][st][r] : 0.f);
      }
  s16x8 pf[2];
#pragma unroll
  for (int m = 0; m < 2; m++) pf[m] = *(const s16x8*)&Pl[w][m][lm][lq * 8];
  // O = q~ S0 + A v (S0^T and v^T B-frags direct from global); wave owns e-tiles {2w,2w+1}
  f32x4 oacc[2][2];
#pragma unroll
  for (int m = 0; m < 2; m++)
#pragma unroll
    for (int ei = 0; ei < 2; ei++) oacc[m][ei] = z4;
#pragma unroll
  for (int ei = 0; ei < 2; ei++) {
    const int et = w * 2 + ei;
    s16x8 vtf = *(const s16x8*)(Vt + ((size_t)(b * 512 + kvh * 128 + et * 16 + lm)) * 2048 +
                                c * 32 + lq * 8);
#pragma unroll
    for (int m = 0; m < 2; m++)
      oacc[m][ei] = __builtin_amdgcn_mfma_f32_16x16x32_bf16(pf[m], vtf, oacc[m][ei], 0, 0, 0);
#pragma unroll
    for (int kk = 0; kk < 4; kk++) {
      s16x8 s0f = *(const s16x8*)(SwsT + cb * 16384 + (et * 16 + lm) * 128 + kk * 32 + lq * 8);
#pragma unroll
      for (int m = 0; m < 2; m++)
        oacc[m][ei] = __builtin_amdgcn_mfma_f32_16x16x32_bf16(qgf[m][kk], s0f, oacc[m][ei], 0, 0, 0);
    }
  }
#pragma unroll
  for (int m = 0; m < 2; m++)
#pragma unroll
    for (int ei = 0; ei < 2; ei++)
#pragma unroll
      for (int r = 0; r < 4; r++)
        Fla[((size_t)(b * 2048 + c * 32 + m * 16 + lq * 4 + r)) * 2048 + h * 128 +
            (w * 2 + ei) * 16 + lm] = f2bfu(scale * oacc[m][ei][r]);
}

// ---------------------------------------------------------------- launch
extern "C" void kernel_launch(void* const* d_in, const int* in_sizes, int n_in,
                              void* d_out, int out_size, void* d_ws, size_t ws_size,
                              hipStream_t stream) {
  const float* X  = (const float*)d_in[0];
  const float* Wq = (const float*)d_in[1];
  const float* Wk = (const float*)d_in[2];
  const float* Wv = (const float*)d_in[3];
  const float* Wo = (const float*)d_in[4];
  float* out = (float*)d_out;

  char* ws = (char*)d_ws;
  size_t off = 0;
  auto alloc = [&](size_t bytes) { void* p = ws + off; off += (bytes + 255) & ~(size_t)255; return p; };
  u16* WoT = (u16*)alloc(2048ull * 2048 * 2);     // 8 MB, live to end
  u16* Qb  = (u16*)alloc(4096ull * 2048 * 2);     // 16 MB
  u16* Kb  = (u16*)alloc(4096ull * 512 * 2);      // 4 MB
  u16* Vb  = (u16*)alloc(4096ull * 512 * 2);      // 4 MB
  u16* Vtb = (u16*)alloc(2ull * 512 * 2048 * 2);  // 4 MB
  u16* Fla = (u16*)alloc(4096ull * 2048 * 2);     // 16 MB
  // time-shared 16 MB region: Xb (until KV proj) -> MT (contrib..prefix) -> AO (flash..end)
  u16* SH16 = (u16*)alloc(4096ull * 2048 * 2);
  u16* Xb = SH16;
  u16* MT = SH16;
  u16* AO = SH16;
  // time-shared scratch: WqT/WkT/WvT early; G/ktilde/SwsT/Lam after projections
  char* BIG = (char*)alloc(26ull * 1024 * 1024);
  u16* WqT = (u16*)BIG;                            // 8 MB
  u16* WkT = (u16*)(BIG + 8ull * 1024 * 1024);     // 2 MB
  u16* WvT = (u16*)(BIG + 10ull * 1024 * 1024);    // 2 MB
  u16* Gg   = (u16*)BIG;                           // 4 MB
  u16* Ktg  = (u16*)(BIG + 4194304ull);            // 4 MB
  u16* SwsT = (u16*)(BIG + 8388608ull);            // 16.78 MB
  float* Lam = (float*)(BIG + 8388608ull + 16777216ull);  // 256 KB
  (void)ws_size; (void)in_sizes; (void)n_in; (void)out_size;

  dim3 blk(256);
  f32_to_bf16<<<dim3(4096), blk, 0, stream>>>(X, Xb, 4096 * 2048 / 8);
  transpose_f32_bf16<<<dim3(64, 64), blk, 0, stream>>>(Wq, WqT, 2048, 2048);
  transpose_f32_bf16<<<dim3(16, 64), blk, 0, stream>>>(Wk, WkT, 2048, 512);
  transpose_f32_bf16<<<dim3(16, 64), blk, 0, stream>>>(Wv, WvT, 2048, 512);
  transpose_f32_bf16<<<dim3(64, 64), blk, 0, stream>>>(Wo, WoT, 2048, 2048);

  gemm_t<<<dim3(16, 32, 1), blk, 0, stream>>>(Xb, WqT, WqT, Qb, Qb, nullptr,
                                              4096, 2048, 2048, nullptr, 0.f);
  gemm_t<<<dim3(4, 32, 2), blk, 0, stream>>>(Xb, WkT, WvT, Kb, Vb, nullptr,
                                             4096, 512, 2048, nullptr, 0.f);

  transpose_bf16<<<dim3(16, 64), blk, 0, stream>>>(Vb, Vtb, 2048, 512);
  transpose_bf16<<<dim3(16, 64), blk, 0, stream>>>(Vb + 2048ull * 512, Vtb + 512ull * 2048, 2048, 512);

  // ---- FLA branch (MT overwrites dead Xb; runs before flash so AO can reuse region)
  fla_contrib32<<<dim3(64, 4, 2), blk, 0, stream>>>(Kb, Vtb, Gg, Ktg, MT, Lam);
  fla_prefix32<<<dim3(8), blk, 0, stream>>>(MT, Lam, SwsT);
  fla_output_mfma<<<dim3(64, 16, 2), blk, 0, stream>>>(Qb, Gg, Ktg, SwsT, Vtb, Fla);

  // ---- base attention (AO overwrites dead MT)
  flash_attn_wave<<<dim3(256), blk, 0, stream>>>(Qb, Kb, Vtb, AO);

  gemm_t<<<dim3(16, 32, 1), blk, 0, stream>>>(AO, WoT, WoT, nullptr, nullptr, out,
                                              4096, 2048, 2048, Fla, 0.01f);
}

// Round 7
// 490.385 us; speedup vs baseline: 1.4024x; 1.4024x over previous
//
#include <hip/hip_runtime.h>
#include <hip/hip_bf16.h>
#include <cstdint>
#include <cstddef>

// ParallelFLAAttention: B=2,N=2048,HID=2048,H=16,KVH=4,D=128,GROUPS=4
// out = softmax_causal(QK^T*s)V @ Wo + 0.01 * GLA(q,k,v)
// I/O f32; internal bf16 MFMA + f32 accum.
// Base attention: fixed-max softmax, wave-autonomous (no barriers/LDS staging).
// FLA: factorized chunk form (T=32): o = q~ S0 + tril(q~ k~^T) v, all MFMA;
// prefix scan parallelized over (bk,e,d) with coalesced, prefetched loads.

typedef __attribute__((ext_vector_type(4))) float f32x4;
typedef __attribute__((ext_vector_type(2))) float f32x2;
typedef __attribute__((ext_vector_type(8))) short s16x8;
typedef unsigned short u16;
typedef unsigned int u32;

__device__ __forceinline__ float bfu2f(u16 u) {
  union { unsigned int i; float f; } x; x.i = ((unsigned int)u) << 16; return x.f;
}
__device__ __forceinline__ u16 f2bfu(float f) {
  union { float f; unsigned int i; } x; x.f = f;
  unsigned int r = x.i + 0x7fffu + ((x.i >> 16) & 1u);
  return (u16)(r >> 16);
}
__device__ __forceinline__ void bf8_to_f(s16x8 v, float* o) {
  union { s16x8 v; u16 u[8]; } x; x.v = v;
#pragma unroll
  for (int j = 0; j < 8; j++) o[j] = bfu2f(x.u[j]);
}
__device__ __forceinline__ s16x8 pack_bf8(f32x4 lo, f32x4 hi) {
  union { s16x8 v; u16 u[8]; } x;
#pragma unroll
  for (int j = 0; j < 4; j++) { x.u[j] = f2bfu(lo[j]); x.u[4 + j] = f2bfu(hi[j]); }
  return x.v;
}
__device__ __forceinline__ void gload_lds16(const u16* g, u16* l) {
  __builtin_amdgcn_global_load_lds(
      (__attribute__((address_space(1))) void*)(g),
      (__attribute__((address_space(3))) void*)(l), 16, 0, 0);
}

// ---------------------------------------------------------------- utility
__global__ __launch_bounds__(256) void f32_to_bf16(
    const float* __restrict__ src, u16* __restrict__ dst, int n8) {
  const int i = blockIdx.x * 256 + threadIdx.x;
  if (i < n8) {
    f32x4 a = *(const f32x4*)(src + (size_t)i * 8);
    f32x4 b = *(const f32x4*)(src + (size_t)i * 8 + 4);
    *(s16x8*)(dst + (size_t)i * 8) = pack_bf8(a, b);
  }
}

// ---------------------------------------------------------------- transposes
__global__ __launch_bounds__(256) void transpose_f32_bf16(
    const float* __restrict__ src, u16* __restrict__ dst, int R, int C) {
  __shared__ u16 tile[32][33];
  const int bx = blockIdx.x * 32, by = blockIdx.y * 32;
  const int tx = threadIdx.x & 31, ty = threadIdx.x >> 5;  // 32 x 8
#pragma unroll
  for (int i = 0; i < 32; i += 8)
    tile[ty + i][tx] = f2bfu(src[(size_t)(by + ty + i) * C + bx + tx]);
  __syncthreads();
#pragma unroll
  for (int i = 0; i < 32; i += 8)
    dst[(size_t)(bx + ty + i) * R + by + tx] = tile[tx][ty + i];
}

__global__ __launch_bounds__(256) void transpose_bf16(
    const u16* __restrict__ src, u16* __restrict__ dst, int R, int C) {
  __shared__ u16 tile[32][33];
  const int bx = blockIdx.x * 32, by = blockIdx.y * 32;
  const int tx = threadIdx.x & 31, ty = threadIdx.x >> 5;
#pragma unroll
  for (int i = 0; i < 32; i += 8)
    tile[ty + i][tx] = src[(size_t)(by + ty + i) * C + bx + tx];
  __syncthreads();
#pragma unroll
  for (int i = 0; i < 32; i += 8)
    dst[(size_t)(bx + ty + i) * R + by + tx] = tile[tx][ty + i];
}

// ---------------------------------------------------------------- GEMM (m97 structure)
__global__ __launch_bounds__(256) void gemm_t(
    const u16* __restrict__ A, const u16* __restrict__ Bt0, const u16* __restrict__ Bt1,
    u16* __restrict__ Cb0, u16* __restrict__ Cb1, float* __restrict__ Cf,
    int M, int N, int K, const u16* __restrict__ addsrc, float addw) {
  __shared__ u16 Al[128 * 32];
  __shared__ u16 Bl[128 * 32];
  const u16* Bt = blockIdx.z ? Bt1 : Bt0;
  u16* Cb = blockIdx.z ? Cb1 : Cb0;
  const int m0 = blockIdx.y * 128, n0 = blockIdx.x * 128;
  const int t = threadIdx.x, w = t >> 6, l = t & 63, lm = l & 15, lq = l >> 4;
  const int wr = w >> 1, wc = w & 1;
  const f32x4 z4 = {0.f, 0.f, 0.f, 0.f};
  f32x4 acc[4][4];
#pragma unroll
  for (int i = 0; i < 4; i++)
#pragma unroll
    for (int j = 0; j < 4; j++) acc[i][j] = z4;
  const int srow = l >> 2, scol = (l & 3) * 8;
  const u16* Ag = A + (size_t)(m0 + w * 32 + srow) * K + scol;
  const u16* Bg = Bt + (size_t)(n0 + w * 32 + srow) * K + scol;
  u16* Alw = &Al[(w * 32) * 32];
  u16* Blw = &Bl[(w * 32) * 32];
  for (int kk = 0; kk < K; kk += 32) {
    gload_lds16(Ag + kk, Alw);
    gload_lds16(Ag + (size_t)16 * K + kk, Alw + 16 * 32);
    gload_lds16(Bg + kk, Blw);
    gload_lds16(Bg + (size_t)16 * K + kk, Blw + 16 * 32);
    __syncthreads();
    s16x8 af[4], bfr[4];
#pragma unroll
    for (int sm = 0; sm < 4; sm++) af[sm] = *(const s16x8*)&Al[(wr * 64 + sm * 16 + lm) * 32 + lq * 8];
#pragma unroll
    for (int sn = 0; sn < 4; sn++) bfr[sn] = *(const s16x8*)&Bl[(wc * 64 + sn * 16 + lm) * 32 + lq * 8];
#pragma unroll
    for (int sm = 0; sm < 4; sm++)
#pragma unroll
      for (int sn = 0; sn < 4; sn++)
        acc[sm][sn] = __builtin_amdgcn_mfma_f32_16x16x32_bf16(af[sm], bfr[sn], acc[sm][sn], 0, 0, 0);
    __syncthreads();
  }
#pragma unroll
  for (int sm = 0; sm < 4; sm++)
#pragma unroll
    for (int sn = 0; sn < 4; sn++)
#pragma unroll
      for (int r = 0; r < 4; r++) {
        const int row = m0 + wr * 64 + sm * 16 + lq * 4 + r;
        const int col = n0 + wc * 64 + sn * 16 + lm;
        float v = acc[sm][sn][r];
        if (Cf) {
          if (addsrc) v += addw * bfu2f(addsrc[(size_t)row * N + col]);
          Cf[(size_t)row * N + col] = v;
        } else {
          Cb[(size_t)row * N + col] = f2bfu(v);
        }
      }
}

// ---------------------------------------------------------------- flash attention, wave-autonomous
__global__ __launch_bounds__(256) void flash_attn_wave(
    const u16* __restrict__ Q, const u16* __restrict__ Kx,
    const u16* __restrict__ Vt, u16* __restrict__ AO) {
  __shared__ u16 Pl[4][2][16][68];
  const int bid = blockIdx.x;
  const int set = bid & 7;               // b*4 + kvh
  const int b = set >> 2, kvh = set & 3;
  const int t = threadIdx.x, w = t >> 6, l = t & 63, lm = l & 15, lq = l >> 4;
  const int wid = (bid >> 3) * 4 + w;    // 0..127 within set
  const int h = kvh * 4 + (wid & 3);
  const int pair = wid >> 2;             // 0..31
  const float scale = 0.0883883476483184f;  // 1/sqrt(128)
  const u16* Kbase = Kx + (size_t)(b * 2048) * 512 + kvh * 128;
  const u16* Vbase = Vt + (size_t)(b * 512 + kvh * 128) * 2048;
  const f32x4 z4 = {0.f, 0.f, 0.f, 0.f};
#pragma unroll 1
  for (int half = 0; half < 2; half++) {
    const int c = half ? (63 - pair) : pair;
    const int base = c * 32;
    const int kthi = c >> 1;
    s16x8 qf[2][4];
#pragma unroll
    for (int m = 0; m < 2; m++)
#pragma unroll
      for (int kk = 0; kk < 4; kk++)
        qf[m][kk] = *(const s16x8*)(Q + ((size_t)(b * 2048 + base + m * 16 + lm)) * 2048 +
                                    h * 128 + kk * 32 + lq * 8);
    f32x4 oacc[2][8];
#pragma unroll
    for (int m = 0; m < 2; m++)
#pragma unroll
      for (int e = 0; e < 8; e++) oacc[m][e] = z4;
    float lsum[2][4] = {{0.f, 0.f, 0.f, 0.f}, {0.f, 0.f, 0.f, 0.f}};
#pragma unroll 1
    for (int kt = 0; kt <= kthi; kt++) {
      const int n0 = kt * 64;
      s16x8 kf[4][4];
#pragma unroll
      for (int nst = 0; nst < 4; nst++)
#pragma unroll
        for (int kk = 0; kk < 4; kk++)
          kf[nst][kk] = *(const s16x8*)(Kbase + (size_t)(n0 + nst * 16 + lm) * 512 +
                                        kk * 32 + lq * 8);
      f32x4 sacc[2][4];
#pragma unroll
      for (int m = 0; m < 2; m++)
#pragma unroll
        for (int i = 0; i < 4; i++) sacc[m][i] = z4;
#pragma unroll
      for (int m = 0; m < 2; m++)
#pragma unroll
        for (int nst = 0; nst < 4; nst++)
#pragma unroll
          for (int kk = 0; kk < 4; kk++)
            sacc[m][nst] = __builtin_amdgcn_mfma_f32_16x16x32_bf16(
                qf[m][kk], kf[nst][kk], sacc[m][nst], 0, 0, 0);
      const bool diag = (kt == kthi);
#pragma unroll
      for (int m = 0; m < 2; m++)
#pragma unroll
        for (int r = 0; r < 4; r++) {
          const int qrow = base + m * 16 + lq * 4 + r;
#pragma unroll
          for (int nst = 0; nst < 4; nst++) {
            float p = __expf(sacc[m][nst][r] * scale);
            if (diag && (n0 + nst * 16 + lm > qrow)) p = 0.f;
            lsum[m][r] += p;
            Pl[w][m][lq * 4 + r][nst * 16 + lm] = f2bfu(p);
          }
        }
      s16x8 vf[8][2];
#pragma unroll
      for (int et = 0; et < 8; et++)
#pragma unroll
        for (int kc = 0; kc < 2; kc++)
          vf[et][kc] = *(const s16x8*)(Vbase + (size_t)(et * 16 + lm) * 2048 +
                                       n0 + kc * 32 + lq * 8);
      s16x8 pf[2][2];
#pragma unroll
      for (int m = 0; m < 2; m++)
#pragma unroll
        for (int kc = 0; kc < 2; kc++)
          pf[m][kc] = *(const s16x8*)&Pl[w][m][lm][kc * 32 + lq * 8];
#pragma unroll
      for (int m = 0; m < 2; m++)
#pragma unroll
        for (int et = 0; et < 8; et++)
#pragma unroll
          for (int kc = 0; kc < 2; kc++)
            oacc[m][et] = __builtin_amdgcn_mfma_f32_16x16x32_bf16(
                pf[m][kc], vf[et][kc], oacc[m][et], 0, 0, 0);
    }
#pragma unroll
    for (int m = 0; m < 2; m++)
#pragma unroll
      for (int r = 0; r < 4; r++) {
#pragma unroll
        for (int off = 1; off < 16; off <<= 1)
          lsum[m][r] += __shfl_xor(lsum[m][r], off, 64);
      }
#pragma unroll
    for (int m = 0; m < 2; m++)
#pragma unroll
      for (int r = 0; r < 4; r++) {
        const float inv = 1.f / lsum[m][r];
        const int row = base + m * 16 + lq * 4 + r;
        u16* op = AO + ((size_t)(b * 2048 + row)) * 2048 + h * 128;
#pragma unroll
        for (int et = 0; et < 8; et++) op[et * 16 + lm] = f2bfu(oacc[m][et][r] * inv);
      }
  }
}

// ---------------------------------------------------------------- FLA: per-32-chunk gates + contribution
__global__ __launch_bounds__(256) void fla_contrib32(
    const u16* __restrict__ Kx, const u16* __restrict__ Vt,
    u16* __restrict__ Gg, u16* __restrict__ Ktg, u16* __restrict__ MT,
    float* __restrict__ Lam) {
  __shared__ float gl[32][132];
  __shared__ float kl[32][132];
  __shared__ float ktl[32][132];
  __shared__ u16 khT[128][40];
  const int c = blockIdx.x, kvh = blockIdx.y, b = blockIdx.z;
  const int bk = b * 4 + kvh;
  const int t = threadIdx.x;
  const size_t cb = (size_t)bk * 64 + c;
  {
    const int r = t >> 3, c0 = (t & 7) * 16;
    const u16* kp = Kx + ((size_t)(b * 2048 + c * 32 + r)) * 512 + kvh * 128 + c0;
#pragma unroll
    for (int i = 0; i < 2; i++) {
      float kv[8];
      bf8_to_f(*(const s16x8*)(kp + i * 8), kv);
#pragma unroll
      for (int j = 0; j < 8; j++) {
        kl[r][c0 + i * 8 + j] = kv[j];
        gl[r][c0 + i * 8 + j] = 1.f / (1.f + __expf(-kv[j]));
      }
    }
  }
  __syncthreads();
  if (t < 128) {  // one thread per d: cumprod + ktilde + khat^T
    float G = 1.f;
#pragma unroll
    for (int s = 0; s < 32; s++) {
      G *= gl[s][t];
      gl[s][t] = G;
      ktl[s][t] = kl[s][t] / G;
    }
    Lam[cb * 128 + t] = G;
    const float lam = G;
#pragma unroll
    for (int s = 0; s < 32; s++) khT[t][s] = f2bfu(ktl[s][t] * lam);
  }
  __syncthreads();
  {
    const int r = t >> 3, c0 = (t & 7) * 16;
    u16* gp = Gg + cb * 4096 + r * 128 + c0;
    u16* kp = Ktg + cb * 4096 + r * 128 + c0;
#pragma unroll
    for (int i = 0; i < 2; i++) {
      f32x4 a = *(f32x4*)&gl[r][c0 + i * 8];
      f32x4 b2 = *(f32x4*)&gl[r][c0 + i * 8 + 4];
      *(s16x8*)(gp + i * 8) = pack_bf8(a, b2);
      a = *(f32x4*)&ktl[r][c0 + i * 8];
      b2 = *(f32x4*)&ktl[r][c0 + i * 8 + 4];
      *(s16x8*)(kp + i * 8) = pack_bf8(a, b2);
    }
  }
  const int w = t >> 6, l = t & 63, lm = l & 15, lq = l >> 4;
  const f32x4 z4 = {0.f, 0.f, 0.f, 0.f};
  f32x4 macc[2][8];
#pragma unroll
  for (int ei = 0; ei < 2; ei++)
#pragma unroll
    for (int dt = 0; dt < 8; dt++) macc[ei][dt] = z4;
  s16x8 vtf[2];
#pragma unroll
  for (int ei = 0; ei < 2; ei++) {
    const int et = w * 2 + ei;
    vtf[ei] = *(const s16x8*)(Vt + ((size_t)(b * 512 + kvh * 128 + et * 16 + lm)) * 2048 +
                              c * 32 + lq * 8);
  }
#pragma unroll
  for (int dt = 0; dt < 8; dt++) {
    s16x8 kf = *(const s16x8*)&khT[dt * 16 + lm][lq * 8];
#pragma unroll
    for (int ei = 0; ei < 2; ei++)
      macc[ei][dt] = __builtin_amdgcn_mfma_f32_16x16x32_bf16(vtf[ei], kf, macc[ei][dt], 0, 0, 0);
  }
  u16* mp = MT + cb * 16384;
#pragma unroll
  for (int ei = 0; ei < 2; ei++)
#pragma unroll
    for (int dt = 0; dt < 8; dt++)
#pragma unroll
      for (int r = 0; r < 4; r++)
        mp[(size_t)((w * 2 + ei) * 16 + lq * 4 + r) * 128 + dt * 16 + lm] =
            f2bfu(macc[ei][dt][r]);
}

// ---------------------------------------------------------------- FLA prefix: parallel over (bk,e,d), coalesced + prefetch
// grid (eg=32, bk=8). thread t: e = eg*4 + (t>>6), d-pair d0 = (t&63)*2.
// Serial only over c (64 chunks); loads for c+1 prefetched during c's FMA.
__global__ __launch_bounds__(256) void fla_prefix32(
    const u16* __restrict__ MT, const float* __restrict__ Lam, u16* __restrict__ SwsT) {
  const int eg = blockIdx.x, bk = blockIdx.y;
  const int t = threadIdx.x;
  const int e = eg * 4 + (t >> 6), d0 = (t & 63) * 2;
  const size_t cb0 = (size_t)bk * 64;
  const u16* mp = MT + cb0 * 16384 + e * 128 + d0;
  const float* lp = Lam + cb0 * 128 + d0;
  u16* sp = SwsT + cb0 * 16384 + e * 128 + d0;
  float s0 = 0.f, s1 = 0.f;
  u32 mnext = *(const u32*)mp;
  f32x2 lnext = *(const f32x2*)lp;
#pragma unroll 1
  for (int c = 0; c < 64; c++) {
    const u32 mcur = mnext;
    const f32x2 lcur = lnext;
    if (c < 63) {  // prefetch next chunk (addresses independent of the scan)
      mnext = *(const u32*)(mp + (size_t)(c + 1) * 16384);
      lnext = *(const f32x2*)(lp + (size_t)(c + 1) * 128);
    }
    // store S_start for chunk c
    *(u32*)(sp + (size_t)c * 16384) = (u32)f2bfu(s0) | ((u32)f2bfu(s1) << 16);
    // S = S*lam + M
    s0 = s0 * lcur[0] + bfu2f((u16)(mcur & 0xffffu));
    s1 = s1 * lcur[1] + bfu2f((u16)(mcur >> 16));
  }
}

// ---------------------------------------------------------------- FLA output: O = scale*(q~ S0 + tril(q~ k~^T) v)
__global__ __launch_bounds__(256) void fla_output_mfma(
    const u16* __restrict__ Q, const u16* __restrict__ Gg, const u16* __restrict__ Ktg,
    const u16* __restrict__ SwsT, const u16* __restrict__ Vt, u16* __restrict__ Fla) {
  __shared__ u16 Pl[4][2][16][40];
  const int c = blockIdx.x, h = blockIdx.y, b = blockIdx.z;
  const int kvh = h >> 2, bk = b * 4 + kvh;
  const int t = threadIdx.x, w = t >> 6, l = t & 63, lm = l & 15, lq = l >> 4;
  const float scale = 0.0883883476483184f;
  const size_t cb = (size_t)bk * 64 + c;
  const f32x4 z4 = {0.f, 0.f, 0.f, 0.f};
  s16x8 qgf[2][4];
#pragma unroll
  for (int m = 0; m < 2; m++)
#pragma unroll
    for (int kk = 0; kk < 4; kk++) {
      float qv[8], gv[8];
      bf8_to_f(*(const s16x8*)(Q + ((size_t)(b * 2048 + c * 32 + m * 16 + lm)) * 2048 +
                               h * 128 + kk * 32 + lq * 8), qv);
      bf8_to_f(*(const s16x8*)(Gg + cb * 4096 + (m * 16 + lm) * 128 + kk * 32 + lq * 8), gv);
      f32x4 a, b2;
#pragma unroll
      for (int j = 0; j < 4; j++) { a[j] = qv[j] * gv[j]; b2[j] = qv[4 + j] * gv[4 + j]; }
      qgf[m][kk] = pack_bf8(a, b2);
    }
  f32x4 sacc[2][2];
#pragma unroll
  for (int m = 0; m < 2; m++)
#pragma unroll
    for (int st = 0; st < 2; st++) sacc[m][st] = z4;
#pragma unroll
  for (int st = 0; st < 2; st++)
#pragma unroll
    for (int kk = 0; kk < 4; kk++) {
      s16x8 ktf = *(const s16x8*)(Ktg + cb * 4096 + (st * 16 + lm) * 128 + kk * 32 + lq * 8);
#pragma unroll
      for (int m = 0; m < 2; m++)
        sacc[m][st] = __builtin_amdgcn_mfma_f32_16x16x32_bf16(qgf[m][kk], ktf, sacc[m][st], 0, 0, 0);
    }
#pragma unroll
  for (int m = 0; m < 2; m++)
#pragma unroll
    for (int st = 0; st < 2; st++)
#pragma unroll
      for (int r = 0; r < 4; r++) {
        const int trow = m * 16 + lq * 4 + r;
        const int scol = st * 16 + lm;
        Pl[w][m][lq * 4 + r][st * 16 + lm] = f2bfu(scol <= trow ? sacc[m][st][r] : 0.f);
      }
  s16x8 pf[2];
#pragma unroll
  for (int m = 0; m < 2; m++) pf[m] = *(const s16x8*)&Pl[w][m][lm][lq * 8];
  f32x4 oacc[2][2];
#pragma unroll
  for (int m = 0; m < 2; m++)
#pragma unroll
    for (int ei = 0; ei < 2; ei++) oacc[m][ei] = z4;
#pragma unroll
  for (int ei = 0; ei < 2; ei++) {
    const int et = w * 2 + ei;
    s16x8 vtf = *(const s16x8*)(Vt + ((size_t)(b * 512 + kvh * 128 + et * 16 + lm)) * 2048 +
                                c * 32 + lq * 8);
#pragma unroll
    for (int m = 0; m < 2; m++)
      oacc[m][ei] = __builtin_amdgcn_mfma_f32_16x16x32_bf16(pf[m], vtf, oacc[m][ei], 0, 0, 0);
#pragma unroll
    for (int kk = 0; kk < 4; kk++) {
      s16x8 s0f = *(const s16x8*)(SwsT + cb * 16384 + (et * 16 + lm) * 128 + kk * 32 + lq * 8);
#pragma unroll
      for (int m = 0; m < 2; m++)
        oacc[m][ei] = __builtin_amdgcn_mfma_f32_16x16x32_bf16(qgf[m][kk], s0f, oacc[m][ei], 0, 0, 0);
    }
  }
#pragma unroll
  for (int m = 0; m < 2; m++)
#pragma unroll
    for (int ei = 0; ei < 2; ei++)
#pragma unroll
      for (int r = 0; r < 4; r++)
        Fla[((size_t)(b * 2048 + c * 32 + m * 16 + lq * 4 + r)) * 2048 + h * 128 +
            (w * 2 + ei) * 16 + lm] = f2bfu(scale * oacc[m][ei][r]);
}

// ---------------------------------------------------------------- launch
extern "C" void kernel_launch(void* const* d_in, const int* in_sizes, int n_in,
                              void* d_out, int out_size, void* d_ws, size_t ws_size,
                              hipStream_t stream) {
  const float* X  = (const float*)d_in[0];
  const float* Wq = (const float*)d_in[1];
  const float* Wk = (const float*)d_in[2];
  const float* Wv = (const float*)d_in[3];
  const float* Wo = (const float*)d_in[4];
  float* out = (float*)d_out;

  char* ws = (char*)d_ws;
  size_t off = 0;
  auto alloc = [&](size_t bytes) { void* p = ws + off; off += (bytes + 255) & ~(size_t)255; return p; };
  u16* WoT = (u16*)alloc(2048ull * 2048 * 2);     // 8 MB, live to end
  u16* Qb  = (u16*)alloc(4096ull * 2048 * 2);     // 16 MB
  u16* Kb  = (u16*)alloc(4096ull * 512 * 2);      // 4 MB
  u16* Vb  = (u16*)alloc(4096ull * 512 * 2);      // 4 MB
  u16* Vtb = (u16*)alloc(2ull * 512 * 2048 * 2);  // 4 MB
  u16* Fla = (u16*)alloc(4096ull * 2048 * 2);     // 16 MB
  // time-shared 16 MB region: Xb (until KV proj) -> MT (contrib..prefix) -> AO (flash..end)
  u16* SH16 = (u16*)alloc(4096ull * 2048 * 2);
  u16* Xb = SH16;
  u16* MT = SH16;
  u16* AO = SH16;
  // time-shared scratch: WqT/WkT/WvT early; G/ktilde/SwsT/Lam after projections
  char* BIG = (char*)alloc(26ull * 1024 * 1024);
  u16* WqT = (u16*)BIG;                            // 8 MB
  u16* WkT = (u16*)(BIG + 8ull * 1024 * 1024);     // 2 MB
  u16* WvT = (u16*)(BIG + 10ull * 1024 * 1024);    // 2 MB
  u16* Gg   = (u16*)BIG;                           // 4 MB
  u16* Ktg  = (u16*)(BIG + 4194304ull);            // 4 MB
  u16* SwsT = (u16*)(BIG + 8388608ull);            // 16.78 MB
  float* Lam = (float*)(BIG + 8388608ull + 16777216ull);  // 256 KB
  (void)ws_size; (void)in_sizes; (void)n_in; (void)out_size;

  dim3 blk(256);
  f32_to_bf16<<<dim3(4096), blk, 0, stream>>>(X, Xb, 4096 * 2048 / 8);
  transpose_f32_bf16<<<dim3(64, 64), blk, 0, stream>>>(Wq, WqT, 2048, 2048);
  transpose_f32_bf16<<<dim3(16, 64), blk, 0, stream>>>(Wk, WkT, 2048, 512);
  transpose_f32_bf16<<<dim3(16, 64), blk, 0, stream>>>(Wv, WvT, 2048, 512);
  transpose_f32_bf16<<<dim3(64, 64), blk, 0, stream>>>(Wo, WoT, 2048, 2048);

  gemm_t<<<dim3(16, 32, 1), blk, 0, stream>>>(Xb, WqT, WqT, Qb, Qb, nullptr,
                                              4096, 2048, 2048, nullptr, 0.f);
  gemm_t<<<dim3(4, 32, 2), blk, 0, stream>>>(Xb, WkT, WvT, Kb, Vb, nullptr,
                                             4096, 512, 2048, nullptr, 0.f);

  transpose_bf16<<<dim3(16, 64), blk, 0, stream>>>(Vb, Vtb, 2048, 512);
  transpose_bf16<<<dim3(16, 64), blk, 0, stream>>>(Vb + 2048ull * 512, Vtb + 512ull * 2048, 2048, 512);

  // ---- FLA branch (MT overwrites dead Xb; AO reuses region after prefix consumes MT)
  fla_contrib32<<<dim3(64, 4, 2), blk, 0, stream>>>(Kb, Vtb, Gg, Ktg, MT, Lam);
  fla_prefix32<<<dim3(32, 8), blk, 0, stream>>>(MT, Lam, SwsT);
  fla_output_mfma<<<dim3(64, 16, 2), blk, 0, stream>>>(Qb, Gg, Ktg, SwsT, Vtb, Fla);

  // ---- base attention (AO overwrites dead MT)
  flash_attn_wave<<<dim3(256), blk, 0, stream>>>(Qb, Kb, Vtb, AO);

  gemm_t<<<dim3(16, 32, 1), blk, 0, stream>>>(AO, WoT, WoT, nullptr, nullptr, out,
                                              4096, 2048, 2048, Fla, 0.01f);
}